// Round 7
// baseline (18759.372 us; speedup 1.0000x reference)
//
#include <hip/hip_runtime.h>

// Problem constants
#define T_LEN 2048
#define I_DIM 128
#define H_DIM 256

// 8 groups (2 dir x 4 batch-tiles of 32) x 32 CUs; grp = wg & 7, cu = wg >> 3.
// Each CU owns hidden cols [cu*8, cu*8+8).
//
// DECOUPLED PAIRS: waves 0-1 run the LSTM recurrence (the only serial chain),
// waves 2-3 run the GRU one step behind. Separate h1/h2 flags; no
// __syncthreads in the loop (LDS pair-barriers only). All cross-CU traffic is
// RELAXED agent-scope atomics (R3/R5-proven coherence; no fences).
//
//   LSTM(s): wait all {h1flag>=s+1, h2flag>=s};  publish h1(s), h1flag=s+2
//   GRU(s):  wait all {h1flag>=s+2, h2flag>=s+1}; publish h2(s), h2flag=s+2
//
// Exchange buffer per (parity, group): 64KB = hi-plane [32 slices][1024B] at
// +0, lo-plane at +32768. Slices 0..15 = h1, 16..31 = h2. Within a slice:
// [2 half][32 b][8 e] bf16 -> lane*16 is the mfma_32x32x16 A-frag.

// LDS offsets (bytes)
#define XB(p)    ((p) * 16384)      // x slices, triple-buffered: hi 8KB + lo 8KB
#define CRED_OFF 49152              // 4 x [32][33] f32 = 16896
#define BAR_OFF  66048              // 2 pair-barrier counters, 64B apart
#define LDS_BYTES 98304             // oversized: forces 1 WG/CU

typedef __attribute__((ext_vector_type(8))) short short8;
typedef __attribute__((ext_vector_type(16))) float f32x16;

__device__ __forceinline__ float sigmoidf_(float v) { return 1.f / (1.f + __expf(-v)); }
__device__ __forceinline__ float tanhf_fast(float v) {
    float t = __expf(-2.f * fabsf(v));
    float r = (1.f - t) / (1.f + t);
    return v < 0.f ? -r : r;
}
__device__ __forceinline__ unsigned short bf16_rne(float f) {
    unsigned u = __float_as_uint(f);
    return (unsigned short)((u + 0x7fffu + ((u >> 16) & 1u)) >> 16);
}
__device__ __forceinline__ void split2(float a, unsigned short& h, unsigned short& l) {
    h = bf16_rne(a);
    float hf = __uint_as_float(((unsigned)h) << 16);
    l = bf16_rne(a - hf);
}
// 16B A-frag as two relaxed agent-scope u64 loads (R5-proven)
__device__ __forceinline__ short8 ld_frag(const char* p) {
    union { unsigned long long u[2]; short8 s; } v;
    v.u[0] = __hip_atomic_load((const unsigned long long*)p,
                               __ATOMIC_RELAXED, __HIP_MEMORY_SCOPE_AGENT);
    v.u[1] = __hip_atomic_load((const unsigned long long*)(p + 8),
                               __ATOMIC_RELAXED, __HIP_MEMORY_SCOPE_AGENT);
    return v.s;
}
// Monotonic LDS pair barrier (128 arrivals per use; targets 128*(instance+1)).
__device__ __forceinline__ void pair_bar(int* c, int target) {
    __threadfence_block();   // order prior LDS/VMEM ops before the arrive
    __hip_atomic_fetch_add(c, 1, __ATOMIC_RELAXED, __HIP_MEMORY_SCOPE_WORKGROUP);
    while (__hip_atomic_load(c, __ATOMIC_RELAXED, __HIP_MEMORY_SCOPE_WORKGROUP) < target) {}
}

__device__ __forceinline__ void stage_unit(const float* __restrict__ x, char* hi, char* lo,
                                           int b0, int teff, int b, int cq) {
    const float4* src = (const float4*)(x + ((size_t)(b0 + b) * T_LEN + teff) * I_DIM + cq * 16);
    float4 v0 = src[0], v1 = src[1], v2 = src[2], v3 = src[3];
    float f[16] = {v0.x, v0.y, v0.z, v0.w, v1.x, v1.y, v1.z, v1.w,
                   v2.x, v2.y, v2.z, v2.w, v3.x, v3.y, v3.z, v3.w};
    short8 H0, H1, L0, L1;
    #pragma unroll
    for (int e = 0; e < 8; ++e) {
        unsigned short h, l;
        split2(f[e], h, l);      H0[e] = (short)h; L0[e] = (short)l;
        split2(f[8 + e], h, l);  H1[e] = (short)h; L1[e] = (short)l;
    }
    char* bh = hi + cq * 1024 + b * 16;
    char* bl = lo + cq * 1024 + b * 16;
    *(short8*)bh = H0; *(short8*)(bh + 512) = H1;
    *(short8*)bl = L0; *(short8*)(bl + 512) = L1;
}

#define MFMA3(ac, ah, al, bh, bl)                                              \
    ac = __builtin_amdgcn_mfma_f32_32x32x16_bf16(ah, bh, ac, 0, 0, 0);         \
    ac = __builtin_amdgcn_mfma_f32_32x32x16_bf16(ah, bl, ac, 0, 0, 0);         \
    ac = __builtin_amdgcn_mfma_f32_32x32x16_bf16(al, bh, ac, 0, 0, 0);

#define ACCSEL(i) ((i & 3) == 0 ? acc0 : (i & 3) == 1 ? acc1 : (i & 3) == 2 ? acc2 : acc3)

__global__ __launch_bounds__(256, 1)
void brnn_persistent(const float* __restrict__ x,
                     const float* __restrict__ w1x, const float* __restrict__ b1x,
                     const float* __restrict__ w1h, const float* __restrict__ b1h,
                     const float* __restrict__ w2x, const float* __restrict__ b2x,
                     const float* __restrict__ w2h, const float* __restrict__ b2h,
                     int* flags, char* exgb, float* h2out)
{
    extern __shared__ char smem_b[];

    const int tid  = threadIdx.x;
    const int lane = tid & 63;
    const int wid  = tid >> 6;         // 0,1 = LSTM pair; 2,3 = GRU pair
    const int wg   = blockIdx.x;
    const int grp  = wg & 7;
    const int cu   = wg >> 3;          // 0..31
    const int dir  = grp >> 2;
    const int btile = grp & 3;
    const int b0   = btile * 32;

    // ---------------- B-fragment preload (weights -> VGPRs, bf16 hi/lo) ------
    // wave0: LSTM K 0..191 (x + h1[0:64)); wave1: LSTM K 192..383 (h1[64:256))
    // wave2: GRU w2x rows (r,z,n,0) over h1;  wave3: GRU w2h rows (r,z,0,n) over h2
    const int nrow = lane & 31;
    const int jrow = nrow >> 2;
    const int q    = nrow & 3;
    const int half = lane >> 5;
    short8 BH[16], BL[16];
    {
        #pragma unroll
        for (int i = 0; i < 16; ++i) {
            short8 H, L;
            #pragma unroll
            for (int e = 0; e < 8; ++e) {
                int kk = i * 16 + half * 8 + e;
                float v = 0.f;
                if (wid == 0) {
                    if (i < 12) {
                        int k = kk;
                        int R = q * H_DIM + cu * 8 + jrow;
                        v = (k < I_DIM) ? w1x[R * I_DIM + k] : w1h[R * H_DIM + (k - I_DIM)];
                    }
                } else if (wid == 1) {
                    if (i < 12) {
                        int k = 192 + kk;
                        int R = q * H_DIM + cu * 8 + jrow;
                        v = w1h[R * H_DIM + (k - I_DIM)];
                    }
                } else if (wid == 2) {
                    if (q < 3) v = w2x[(q * H_DIM + cu * 8 + jrow) * H_DIM + kk];
                } else {
                    if (q == 0)      v = w2h[(0 * H_DIM + cu * 8 + jrow) * H_DIM + kk];
                    else if (q == 1) v = w2h[(1 * H_DIM + cu * 8 + jrow) * H_DIM + kk];
                    else if (q == 3) v = w2h[(2 * H_DIM + cu * 8 + jrow) * H_DIM + kk];
                }
                unsigned short hh, ll;
                split2(v, hh, ll);
                H[e] = (short)hh; L[e] = (short)ll;
            }
            BH[i] = H; BL[i] = L;
        }
    }

    // ---------------- nonlin-owner constants: 2 states per thread ------------
    // LSTM: threads 0..127; GRU: threads 128..255. (bbn, qn) -> j = 2*qn+{0,1}
    const int tt  = (tid < 128) ? tid : (tid - 128);
    const int bbn = tt & 31;
    const int qn  = tt >> 5;           // 0..3
    float biasA[2][4];
    #pragma unroll
    for (int e = 0; e < 2; ++e) {
        int jg = cu * 8 + 2 * qn + e;
        if (tid < 128) {
            #pragma unroll
            for (int g = 0; g < 4; ++g)
                biasA[e][g] = b1x[g * H_DIM + jg] + b1h[g * H_DIM + jg];
        } else {
            biasA[e][0] = b2x[0 * H_DIM + jg] + b2h[0 * H_DIM + jg];
            biasA[e][1] = b2x[1 * H_DIM + jg] + b2h[1 * H_DIM + jg];
            biasA[e][2] = b2x[2 * H_DIM + jg];
            biasA[e][3] = b2h[2 * H_DIM + jg];
        }
    }
    float st[2] = {0.f, 0.f};          // c-state (LSTM threads) / h2-state (GRU threads)

    int* lstm_bar = (int*)(smem_b + BAR_OFF);
    int* gru_bar  = (int*)(smem_b + BAR_OFF + 64);
    int* h1f = flags + grp * 128;       // [32] per-CU h1 flags
    int* h2f = flags + grp * 128 + 64;  // [32] per-CU h2 flags

    // ---------------- init ---------------------------------------------------
    if (tid < 2) *(int*)(smem_b + BAR_OFF + tid * 64) = 0;
    {   // zero own h1 & h2 blocks in parity-1 buffer (read at s=0), both planes
        char* p1 = exgb + (size_t)(8 + grp) * 65536;
        int r = tid >> 6, w = (tid & 63) * 8;
        int off = (r & 1) * 32768 + ((r >> 1) * 16 + (cu >> 1)) * 1024 + (cu & 1) * 512 + w;
        __hip_atomic_store((unsigned long long*)(p1 + off), 0ull,
                           __ATOMIC_RELAXED, __HIP_MEMORY_SCOPE_AGENT);
    }
    {   // stage x(0) -> buf0 and x(1) -> buf1
        int b = tid >> 3, cq = tid & 7;
        stage_unit(x, smem_b + XB(0), smem_b + XB(0) + 8192, b0, dir ? (T_LEN - 1) : 0, b, cq);
        stage_unit(x, smem_b + XB(1), smem_b + XB(1) + 8192, b0, dir ? (T_LEN - 2) : 1, b, cq);
    }
    __syncthreads();   // drains all init stores (the only workgroup barrier)
    if (tid == 0) {
        __hip_atomic_store(&h1f[cu], 1, __ATOMIC_RELAXED, __HIP_MEMORY_SCOPE_AGENT);
        __hip_atomic_store(&h2f[cu], 1, __ATOMIC_RELAXED, __HIP_MEMORY_SCOPE_AGENT);
    }

    for (int s = 0; s < T_LEN; ++s) {
        // ---------------- poll (both waves of each pair) ---------------------
        {
            int t1 = (wid < 2) ? (s + 1) : (s + 2);   // h1flag target
            int t2 = (wid < 2) ? s : (s + 1);         // h2flag target
            const int* fp = (lane < 32) ? &h1f[lane] : &h2f[lane - 32];
            int tgt = (lane < 32) ? t1 : t2;
            while (true) {
                int v = __hip_atomic_load(fp, __ATOMIC_RELAXED, __HIP_MEMORY_SCOPE_AGENT);
                if (__all(v >= tgt)) break;
            }
        }
        const char* exgPrev = exgb + (size_t)((((s + 1) & 1)) * 8 + grp) * 65536;  // h1(s-1), h2(s-1)
        char*       exgCur  = exgb + (size_t)(((s & 1)) * 8 + grp) * 65536;        // h1(s), h2(s)

        // ---------------- MFMA phase ----------------------------------------
        f32x16 acc0, acc1, acc2, acc3;
        #pragma unroll
        for (int r = 0; r < 16; ++r) { acc0[r] = 0.f; acc1[r] = 0.f; acc2[r] = 0.f; acc3[r] = 0.f; }

        if (wid == 0) {
            short8 hA[4], lA[4];
            #pragma unroll
            for (int i = 0; i < 4; ++i) {
                hA[i] = ld_frag(exgPrev + i * 1024 + lane * 16);
                lA[i] = ld_frag(exgPrev + 32768 + i * 1024 + lane * 16);
            }
            const char* xh = smem_b + XB(s % 3);
            const char* xl = xh + 8192;
            #pragma unroll
            for (int i = 0; i < 8; ++i) {   // x part from LDS while h-frags fly
                short8 ah = *(const short8*)(xh + i * 1024 + lane * 16);
                short8 al = *(const short8*)(xl + i * 1024 + lane * 16);
                f32x16& ac = ACCSEL(i);
                MFMA3(ac, ah, al, BH[i], BL[i]);
            }
            #pragma unroll
            for (int i = 0; i < 4; ++i) {
                f32x16& ac = ACCSEL(8 + i);
                MFMA3(ac, hA[i], lA[i], BH[8 + i], BL[8 + i]);
            }
        } else if (wid == 1) {
            short8 hA[12], lA[12];
            #pragma unroll
            for (int i = 0; i < 12; ++i) {
                hA[i] = ld_frag(exgPrev + (4 + i) * 1024 + lane * 16);
                lA[i] = ld_frag(exgPrev + 32768 + (4 + i) * 1024 + lane * 16);
            }
            #pragma unroll
            for (int i = 0; i < 12; ++i) {
                f32x16& ac = ACCSEL(i);
                MFMA3(ac, hA[i], lA[i], BH[i], BL[i]);
            }
        } else if (wid == 2) {               // GRU x-side: h1(s) from exgCur
            short8 hA[16], lA[16];
            #pragma unroll
            for (int i = 0; i < 16; ++i) {
                hA[i] = ld_frag(exgCur + i * 1024 + lane * 16);
                lA[i] = ld_frag(exgCur + 32768 + i * 1024 + lane * 16);
            }
            #pragma unroll
            for (int i = 0; i < 16; ++i) {
                f32x16& ac = ACCSEL(i);
                MFMA3(ac, hA[i], lA[i], BH[i], BL[i]);
            }
        } else {                             // GRU h-side: h2(s-1) from exgPrev
            short8 hA[16], lA[16];
            #pragma unroll
            for (int i = 0; i < 16; ++i) {
                hA[i] = ld_frag(exgPrev + (16 + i) * 1024 + lane * 16);
                lA[i] = ld_frag(exgPrev + 32768 + (16 + i) * 1024 + lane * 16);
            }
            #pragma unroll
            for (int i = 0; i < 16; ++i) {
                f32x16& ac = ACCSEL(i);
                MFMA3(ac, hA[i], lA[i], BH[i], BL[i]);
            }
        }
        // C write -> cred[wid]
        {
            float* credw = (float*)(smem_b + CRED_OFF) + wid * 1056;
            #pragma unroll
            for (int r = 0; r < 16; ++r) {
                int b = (r & 3) + 8 * (r >> 2) + 4 * half;
                credw[nrow * 33 + b] = acc0[r] + acc1[r] + acc2[r] + acc3[r];
            }
        }
        int* bar = (wid < 2) ? lstm_bar : gru_bar;
        pair_bar(bar, 128 * (2 * s + 1));

        // ---------------- nonlinearity + publish (2 states/thread) -----------
        const float* cr = (const float*)(smem_b + CRED_OFF);
        #define CRD(w, jj, g) cr[(w) * 1056 + ((jj) * 4 + (g)) * 33 + bbn]
        if (tid < 128) {
            // LSTM
            unsigned hi32 = 0, lo32 = 0;
            #pragma unroll
            for (int e = 0; e < 2; ++e) {
                int jj = 2 * qn + e;
                float gi = CRD(0, jj, 0) + CRD(1, jj, 0) + biasA[e][0];
                float gf = CRD(0, jj, 1) + CRD(1, jj, 1) + biasA[e][1];
                float gg = CRD(0, jj, 2) + CRD(1, jj, 2) + biasA[e][2];
                float go = CRD(0, jj, 3) + CRD(1, jj, 3) + biasA[e][3];
                float ig = sigmoidf_(gi), fg = sigmoidf_(gf);
                float cg = tanhf_fast(gg), og = sigmoidf_(go);
                st[e] = st[e] * fg + ig * cg;
                float h1v = og * tanhf_fast(st[e]);
                unsigned short h, l;
                split2(h1v, h, l);
                hi32 |= ((unsigned)h) << (16 * e);
                lo32 |= ((unsigned)l) << (16 * e);
            }
            int off = (cu >> 1) * 1024 + (cu & 1) * 512 + bbn * 16 + qn * 4;
            __hip_atomic_store((unsigned*)(exgCur + off), hi32,
                               __ATOMIC_RELAXED, __HIP_MEMORY_SCOPE_AGENT);
            __hip_atomic_store((unsigned*)(exgCur + 32768 + off), lo32,
                               __ATOMIC_RELAXED, __HIP_MEMORY_SCOPE_AGENT);
            asm volatile("s_waitcnt vmcnt(0)" ::: "memory");
            pair_bar(bar, 128 * (2 * s + 2));
            if (tid == 0)
                __hip_atomic_store(&h1f[cu], s + 2, __ATOMIC_RELAXED, __HIP_MEMORY_SCOPE_AGENT);
            // wave1: stage x(s+2) into buf (s+2)%3 (off-chain; synced to wave0's
            // read at step s+2 through the bar1/bar2 fences of step s+1)
            if (wid == 1 && s + 2 < T_LEN) {
                int teff = dir ? (T_LEN - 3 - s) : (s + 2);
                char* xh = smem_b + XB((s + 2) % 3);
                char* xl = xh + 8192;
                int t2i = tid - 64;
                #pragma unroll
                for (int i = 0; i < 4; ++i) {
                    int u = i * 64 + t2i;
                    stage_unit(x, xh, xl, b0, teff, u >> 3, u & 7);
                }
            }
        } else {
            // GRU
            unsigned hi32 = 0, lo32 = 0;
            #pragma unroll
            for (int e = 0; e < 2; ++e) {
                int jj = 2 * qn + e;
                float rc = CRD(2, jj, 0) + CRD(3, jj, 0) + biasA[e][0];
                float zc = CRD(2, jj, 1) + CRD(3, jj, 1) + biasA[e][1];
                float xn = CRD(2, jj, 2) + CRD(3, jj, 2) + biasA[e][2];
                float hn = CRD(2, jj, 3) + CRD(3, jj, 3) + biasA[e][3];
                float rg = sigmoidf_(rc), zg = sigmoidf_(zc);
                float ng = tanhf_fast(xn + rg * hn);
                st[e] = zg * st[e] + (1.f - zg) * ng;
                unsigned short h, l;
                split2(st[e], h, l);
                hi32 |= ((unsigned)h) << (16 * e);
                lo32 |= ((unsigned)l) << (16 * e);
            }
            if (s == T_LEN - 1) {
                h2out[(size_t)(grp * 32 + bbn) * H_DIM + cu * 8 + 2 * qn]     = st[0];
                h2out[(size_t)(grp * 32 + bbn) * H_DIM + cu * 8 + 2 * qn + 1] = st[1];
            } else {
                int off = 16384 + (cu >> 1) * 1024 + (cu & 1) * 512 + bbn * 16 + qn * 4;
                __hip_atomic_store((unsigned*)(exgCur + off), hi32,
                                   __ATOMIC_RELAXED, __HIP_MEMORY_SCOPE_AGENT);
                __hip_atomic_store((unsigned*)(exgCur + 32768 + off), lo32,
                                   __ATOMIC_RELAXED, __HIP_MEMORY_SCOPE_AGENT);
            }
            asm volatile("s_waitcnt vmcnt(0)" ::: "memory");
            pair_bar(bar, 128 * (2 * s + 2));
            if (tid == 128 && s < T_LEN - 1)
                __hip_atomic_store(&h2f[cu], s + 2, __ATOMIC_RELAXED, __HIP_MEMORY_SCOPE_AGENT);
        }
        #undef CRD
    }
}

// out[b][o] = concat(h_fwd[b], h_bwd[b]) . wo[o] + bo[o]
__global__ __launch_bounds__(128)
void brnn_out(const float* __restrict__ h2out, const float* __restrict__ wo,
              const float* __restrict__ bo, float* __restrict__ out)
{
    __shared__ float hc[512];
    int b = blockIdx.x;
    int o = threadIdx.x;
    int btile = b >> 5, bi = b & 31;
    for (int k = threadIdx.x; k < 256; k += 128) {
        hc[k]       = h2out[((size_t)(btile)     * 32 + bi) * H_DIM + k];
        hc[256 + k] = h2out[((size_t)(4 + btile) * 32 + bi) * H_DIM + k];
    }
    __syncthreads();
    float acc = bo[o];
    const float4* w4 = (const float4*)&wo[(size_t)o * 512];
    #pragma unroll 8
    for (int k = 0; k < 128; ++k) {
        float4 w = w4[k];
        acc += w.x * hc[k * 4] + w.y * hc[k * 4 + 1] + w.z * hc[k * 4 + 2] + w.w * hc[k * 4 + 3];
    }
    out[b * 128 + o] = acc;
}

extern "C" void kernel_launch(void* const* d_in, const int* in_sizes, int n_in,
                              void* d_out, int out_size, void* d_ws, size_t ws_size,
                              hipStream_t stream) {
    const float* x   = (const float*)d_in[0];
    const float* w1x = (const float*)d_in[1];
    const float* b1x = (const float*)d_in[2];
    const float* w1h = (const float*)d_in[3];
    const float* b1h = (const float*)d_in[4];
    const float* w2x = (const float*)d_in[5];
    const float* b2x = (const float*)d_in[6];
    const float* w2h = (const float*)d_in[7];
    const float* b2h = (const float*)d_in[8];
    const float* wo  = (const float*)d_in[9];
    const float* bo  = (const float*)d_in[10];
    float* out = (float*)d_out;

    char* ws = (char*)d_ws;
    int* flags = (int*)ws;                          // 8 grp x 128 ints (h1 at +0, h2 at +64)
    char* exgb = ws + 8192;                         // 2 par x 8 grp x 64KB = 1MB
    float* h2out = (float*)(ws + 8192 + 1048576);   // 256 x 256 f32 = 256KB

    hipMemsetAsync(flags, 0, 8 * 128 * sizeof(int), stream);

    size_t shmem = LDS_BYTES;
    hipFuncSetAttribute((const void*)brnn_persistent,
                        hipFuncAttributeMaxDynamicSharedMemorySize, (int)shmem);

    void* args[] = { (void*)&x, (void*)&w1x, (void*)&b1x, (void*)&w1h, (void*)&b1h,
                     (void*)&w2x, (void*)&b2x, (void*)&w2h, (void*)&b2h,
                     (void*)&flags, (void*)&exgb, (void*)&h2out };
    hipError_t err = hipLaunchCooperativeKernel((void*)brnn_persistent,
                                                dim3(256), dim3(256), args,
                                                (unsigned int)shmem, stream);
    if (err != hipSuccess) {
        brnn_persistent<<<dim3(256), dim3(256), shmem, stream>>>(
            x, w1x, b1x, w1h, b1h, w2x, b2x, w2h, b2h, flags, exgb, h2out);
    }

    brnn_out<<<dim3(128), dim3(128), 0, stream>>>(h2out, wo, bo, out);
}

// Round 8
// 17092.603 us; speedup vs baseline: 1.0975x; 1.0975x over previous
//
#include <hip/hip_runtime.h>

// Problem constants
#define T_LEN 2048
#define I_DIM 128
#define H_DIM 256

// 8 groups (2 dir x 4 batch-tiles of 32) x 32 CUs; grp = wg & 7, cu = wg >> 3.
// Each CU owns hidden cols [cu*8, cu*8+8).
//
// R5 schedule (step s: LSTM(s) + GRU(s-1)), wave-specialized:
//   w0 = LSTM owner: h1[64:256) MFMA, nonlin, publish h1(s), h1f := s+2
//   w1 = LSTM helper: x-part + h1[0:64) MFMA -> LDS partial; stages x(s+1)
//   w2 = GRU owner: h2-side MFMA, nonlin, publish h2(s-1), h2f := s+2
//   w3 = GRU helper: h1-side MFMA -> LDS partial
// No __syncthreads in the loop. Cross-CU: relaxed agent atomics only.
// Intra-CU: LDS monotone counters (goL, done1, goG, done3).
//
// Waits: w0: h1f>=s+1 (data h1(s-1)) && h2f>=s (overwrite guard, slack-1 via
//            TRIPLE-buffered h1).  w2: h1f>=s+1 && h2f>=s+1.
//
// Exchange per group (163840 B): h1 parity p(0..2) at p*32768 (hi 16KB, lo
// +16384); h2 parity q(0..1) at 98304 + q*32768. Slice: [2 khalf][32 b][8 e]
// bf16; lane*16 = mfma_32x32x16 A-frag. h1(t) -> parity t%3; h2(t) -> (t+1)&1.

// LDS offsets (bytes)
#define XB(p)    ((p) * 16384)      // 2 x-bufs: hi 8KB + lo 8KB
#define CRED_OFF 32768              // 4 x 1056 f32 = 16896
#define CTR_OFF  49664              // goL,done1,goG,done3 @ 64B apart
#define LDS_BYTES 98304             // oversized: forces 1 WG/CU

typedef __attribute__((ext_vector_type(8))) short short8;
typedef __attribute__((ext_vector_type(16))) float f32x16;

__device__ __forceinline__ float sigmoidf_(float v) { return 1.f / (1.f + __expf(-v)); }
__device__ __forceinline__ float tanhf_fast(float v) {
    float t = __expf(-2.f * fabsf(v));
    float r = (1.f - t) / (1.f + t);
    return v < 0.f ? -r : r;
}
__device__ __forceinline__ unsigned short bf16_rne(float f) {
    unsigned u = __float_as_uint(f);
    return (unsigned short)((u + 0x7fffu + ((u >> 16) & 1u)) >> 16);
}
__device__ __forceinline__ void split2(float a, unsigned short& h, unsigned short& l) {
    h = bf16_rne(a);
    float hf = __uint_as_float(((unsigned)h) << 16);
    l = bf16_rne(a - hf);
}
// 16B A-frag as two relaxed agent-scope u64 loads (R3/R5-proven coherence)
__device__ __forceinline__ short8 ld_frag(const char* p) {
    union { unsigned long long u[2]; short8 s; } v;
    v.u[0] = __hip_atomic_load((const unsigned long long*)p,
                               __ATOMIC_RELAXED, __HIP_MEMORY_SCOPE_AGENT);
    v.u[1] = __hip_atomic_load((const unsigned long long*)(p + 8),
                               __ATOMIC_RELAXED, __HIP_MEMORY_SCOPE_AGENT);
    return v.s;
}
__device__ __forceinline__ int lds_ld(const int* c) {
    return __hip_atomic_load(c, __ATOMIC_RELAXED, __HIP_MEMORY_SCOPE_WORKGROUP);
}
__device__ __forceinline__ void lds_st(int* c, int v) {
    __hip_atomic_store(c, v, __ATOMIC_RELAXED, __HIP_MEMORY_SCOPE_WORKGROUP);
}

__device__ __forceinline__ void stage_unit(const float* __restrict__ x, char* hi, char* lo,
                                           int b0, int teff, int b, int cq) {
    const float4* src = (const float4*)(x + ((size_t)(b0 + b) * T_LEN + teff) * I_DIM + cq * 16);
    float4 v0 = src[0], v1 = src[1], v2 = src[2], v3 = src[3];
    float f[16] = {v0.x, v0.y, v0.z, v0.w, v1.x, v1.y, v1.z, v1.w,
                   v2.x, v2.y, v2.z, v2.w, v3.x, v3.y, v3.z, v3.w};
    short8 H0, H1, L0, L1;
    #pragma unroll
    for (int e = 0; e < 8; ++e) {
        unsigned short h, l;
        split2(f[e], h, l);      H0[e] = (short)h; L0[e] = (short)l;
        split2(f[8 + e], h, l);  H1[e] = (short)h; L1[e] = (short)l;
    }
    char* bh = hi + cq * 1024 + b * 16;
    char* bl = lo + cq * 1024 + b * 16;
    *(short8*)bh = H0; *(short8*)(bh + 512) = H1;
    *(short8*)bl = L0; *(short8*)(bl + 512) = L1;
}

#define MFMA3(ac, ah, al, bh, bl)                                              \
    ac = __builtin_amdgcn_mfma_f32_32x32x16_bf16(ah, bh, ac, 0, 0, 0);         \
    ac = __builtin_amdgcn_mfma_f32_32x32x16_bf16(ah, bl, ac, 0, 0, 0);         \
    ac = __builtin_amdgcn_mfma_f32_32x32x16_bf16(al, bh, ac, 0, 0, 0);

#define ACCSEL(i) ((i & 3) == 0 ? acc0 : (i & 3) == 1 ? acc1 : (i & 3) == 2 ? acc2 : acc3)

__global__ __launch_bounds__(256, 1)
void brnn_persistent(const float* __restrict__ x,
                     const float* __restrict__ w1x, const float* __restrict__ b1x,
                     const float* __restrict__ w1h, const float* __restrict__ b1h,
                     const float* __restrict__ w2x, const float* __restrict__ b2x,
                     const float* __restrict__ w2h, const float* __restrict__ b2h,
                     int* flags, char* exgb, float* h2out)
{
    extern __shared__ char smem_b[];

    const int tid  = threadIdx.x;
    const int lane = tid & 63;
    const int wid  = tid >> 6;
    const int wg   = blockIdx.x;
    const int grp  = wg & 7;
    const int cu   = wg >> 3;
    const int dir  = grp >> 2;
    const int btile = grp & 3;
    const int b0   = btile * 32;

    char* gb = exgb + (size_t)grp * 163840;
    int* h1f = flags + grp * 64;
    int* h2f = h1f + 32;
    int* goL   = (int*)(smem_b + CTR_OFF);
    int* done1 = (int*)(smem_b + CTR_OFF + 64);
    int* goG   = (int*)(smem_b + CTR_OFF + 128);
    int* done3 = (int*)(smem_b + CTR_OFF + 192);
    float* cred = (float*)(smem_b + CRED_OFF);

    const int nrow = lane & 31;
    const int jrow = nrow >> 2;
    const int q    = nrow & 3;
    const int half = lane >> 5;
    const int hl   = lane >> 5;        // owner: which j-quad (j = 4*hl + e)
    const int bb   = lane & 31;        // owner: batch row

    // ---------------- init (all threads) ------------------------------------
    if (tid < 4) lds_st((int*)(smem_b + CTR_OFF + tid * 64), 0);
    if (tid < 128) {   // zero h1(-1) own slice at parity 2, both planes
        char* p2 = gb + 2 * 32768 + ((tid >> 6) ? 16384 : 0)
                 + (cu >> 1) * 1024 + (cu & 1) * 512 + (tid & 63) * 8;
        __hip_atomic_store((unsigned long long*)p2, 0ull,
                           __ATOMIC_RELAXED, __HIP_MEMORY_SCOPE_AGENT);
    }
    stage_unit(x, smem_b + XB(0), smem_b + XB(0) + 8192, b0,
               dir ? (T_LEN - 1) : 0, tid >> 3, tid & 7);
    __syncthreads();   // drains init stores
    if (tid == 0) __hip_atomic_store(&h1f[cu], 1, __ATOMIC_RELAXED, __HIP_MEMORY_SCOPE_AGENT);

    if (wid == 0) {
        // ================= LSTM OWNER: h1[64:256), nonlin, publish ===========
        short8 BH[12], BL[12];
        #pragma unroll
        for (int i = 0; i < 12; ++i) {
            short8 H, L;
            #pragma unroll
            for (int e = 0; e < 8; ++e) {
                int k = 192 + i * 16 + half * 8 + e;
                int R = q * H_DIM + cu * 8 + jrow;
                unsigned short hh, ll;
                split2(w1h[R * H_DIM + (k - I_DIM)], hh, ll);
                H[e] = (short)hh; L[e] = (short)ll;
            }
            BH[i] = H; BL[i] = L;
        }
        float biasv[4][4];
        #pragma unroll
        for (int e = 0; e < 4; ++e) {
            int jg = cu * 8 + 4 * hl + e;
            #pragma unroll
            for (int g = 0; g < 4; ++g)
                biasv[e][g] = b1x[g * H_DIM + jg] + b1h[g * H_DIM + jg];
        }
        float cst[4] = {0.f, 0.f, 0.f, 0.f};
        float* cred0 = cred;

        for (int s = 0; s < T_LEN; ++s) {
            {   // poll: h1f >= s+1 (data), h2f >= s (overwrite guard, slack-1)
                const int* fp = (lane < 32) ? &h1f[lane] : &h2f[lane - 32];
                int tgt = (lane < 32) ? (s + 1) : s;
                while (true) {
                    int v = __hip_atomic_load(fp, __ATOMIC_RELAXED, __HIP_MEMORY_SCOPE_AGENT);
                    if (__all(v >= tgt)) break;
                }
            }
            if (lane == 0) lds_st(goL, s + 1);
            const char* h1r = gb + ((s + 2) % 3) * 32768;
            short8 hA[12], lA[12];
            #pragma unroll
            for (int i = 0; i < 12; ++i) {
                hA[i] = ld_frag(h1r + (4 + i) * 1024 + lane * 16);
                lA[i] = ld_frag(h1r + 16384 + (4 + i) * 1024 + lane * 16);
            }
            f32x16 acc0, acc1, acc2, acc3;
            #pragma unroll
            for (int r = 0; r < 16; ++r) { acc0[r]=0.f; acc1[r]=0.f; acc2[r]=0.f; acc3[r]=0.f; }
            #pragma unroll
            for (int i = 0; i < 12; ++i) { f32x16& ac = ACCSEL(i); MFMA3(ac, hA[i], lA[i], BH[i], BL[i]); }
            #pragma unroll
            for (int r = 0; r < 16; ++r) {
                int b = (r & 3) + 8 * (r >> 2) + 4 * half;
                cred0[nrow * 33 + b] = acc0[r] + acc1[r] + acc2[r] + acc3[r];
            }
            while (lds_ld(done1) < s + 1) {}
            __threadfence_block();
            unsigned long long hi64 = 0, lo64 = 0;
            #pragma unroll
            for (int e = 0; e < 4; ++e) {
                int jj = 4 * hl + e;
                float gi = cred[(jj*4+0)*33+bb] + cred[1056+(jj*4+0)*33+bb] + biasv[e][0];
                float gf = cred[(jj*4+1)*33+bb] + cred[1056+(jj*4+1)*33+bb] + biasv[e][1];
                float gg = cred[(jj*4+2)*33+bb] + cred[1056+(jj*4+2)*33+bb] + biasv[e][2];
                float go = cred[(jj*4+3)*33+bb] + cred[1056+(jj*4+3)*33+bb] + biasv[e][3];
                float ig = sigmoidf_(gi), fg = sigmoidf_(gf);
                float cg = tanhf_fast(gg), og = sigmoidf_(go);
                cst[e] = cst[e] * fg + ig * cg;
                float h1v = og * tanhf_fast(cst[e]);
                unsigned short h, l;
                split2(h1v, h, l);
                hi64 |= ((unsigned long long)h) << (16 * e);
                lo64 |= ((unsigned long long)l) << (16 * e);
            }
            char* h1w = gb + (s % 3) * 32768;
            int off = (cu >> 1) * 1024 + (cu & 1) * 512 + bb * 16 + hl * 8;
            __hip_atomic_store((unsigned long long*)(h1w + off), hi64,
                               __ATOMIC_RELAXED, __HIP_MEMORY_SCOPE_AGENT);
            __hip_atomic_store((unsigned long long*)(h1w + 16384 + off), lo64,
                               __ATOMIC_RELAXED, __HIP_MEMORY_SCOPE_AGENT);
            asm volatile("s_waitcnt vmcnt(0)" ::: "memory");
            if (lane == 0)
                __hip_atomic_store(&h1f[cu], s + 2, __ATOMIC_RELAXED, __HIP_MEMORY_SCOPE_AGENT);
        }
    } else if (wid == 1) {
        // ================= LSTM HELPER: x + h1[0:64) -> cred1; x stager ======
        short8 BH[12], BL[12];
        #pragma unroll
        for (int i = 0; i < 12; ++i) {
            short8 H, L;
            #pragma unroll
            for (int e = 0; e < 8; ++e) {
                int k = i * 16 + half * 8 + e;
                int R = q * H_DIM + cu * 8 + jrow;
                float v = (k < I_DIM) ? w1x[R * I_DIM + k] : w1h[R * H_DIM + (k - I_DIM)];
                unsigned short hh, ll;
                split2(v, hh, ll);
                H[e] = (short)hh; L[e] = (short)ll;
            }
            BH[i] = H; BL[i] = L;
        }
        float* cred1 = cred + 1056;
        for (int s = 0; s < T_LEN; ++s) {
            while (lds_ld(goL) < s + 1) {}
            __threadfence_block();
            const char* h1r = gb + ((s + 2) % 3) * 32768;
            short8 hA[4], lA[4];
            #pragma unroll
            for (int i = 0; i < 4; ++i) {
                hA[i] = ld_frag(h1r + i * 1024 + lane * 16);
                lA[i] = ld_frag(h1r + 16384 + i * 1024 + lane * 16);
            }
            const char* xh = smem_b + XB(s & 1);
            const char* xl = xh + 8192;
            f32x16 acc0, acc1, acc2, acc3;
            #pragma unroll
            for (int r = 0; r < 16; ++r) { acc0[r]=0.f; acc1[r]=0.f; acc2[r]=0.f; acc3[r]=0.f; }
            #pragma unroll
            for (int i = 0; i < 8; ++i) {
                short8 ah = *(const short8*)(xh + i * 1024 + lane * 16);
                short8 al = *(const short8*)(xl + i * 1024 + lane * 16);
                f32x16& ac = ACCSEL(i);
                MFMA3(ac, ah, al, BH[i], BL[i]);
            }
            #pragma unroll
            for (int i = 0; i < 4; ++i) { f32x16& ac = ACCSEL(8 + i); MFMA3(ac, hA[i], lA[i], BH[8 + i], BL[8 + i]); }
            #pragma unroll
            for (int r = 0; r < 16; ++r) {
                int b = (r & 3) + 8 * (r >> 2) + 4 * half;
                cred1[nrow * 33 + b] = acc0[r] + acc1[r] + acc2[r] + acc3[r];
            }
            __threadfence_block();
            if (lane == 0) lds_st(done1, s + 1);
            if (s + 1 < T_LEN) {   // stage x(s+1) (self-consumed next step)
                int teff = dir ? (T_LEN - 2 - s) : (s + 1);
                char* nxh = smem_b + XB((s + 1) & 1);
                char* nxl = nxh + 8192;
                #pragma unroll
                for (int i = 0; i < 4; ++i) {
                    int u = i * 64 + lane;
                    stage_unit(x, nxh, nxl, b0, teff, u >> 3, u & 7);
                }
            }
        }
    } else if (wid == 2) {
        // ================= GRU OWNER: h2-side, nonlin, publish h2(s-1) =======
        short8 BH[16], BL[16];
        #pragma unroll
        for (int i = 0; i < 16; ++i) {
            short8 H, L;
            #pragma unroll
            for (int e = 0; e < 8; ++e) {
                int kk = i * 16 + half * 8 + e;
                float v = 0.f;
                if (q == 0)      v = w2h[(0 * H_DIM + cu * 8 + jrow) * H_DIM + kk];
                else if (q == 1) v = w2h[(1 * H_DIM + cu * 8 + jrow) * H_DIM + kk];
                else if (q == 3) v = w2h[(2 * H_DIM + cu * 8 + jrow) * H_DIM + kk];
                unsigned short hh, ll;
                split2(v, hh, ll);
                H[e] = (short)hh; L[e] = (short)ll;
            }
            BH[i] = H; BL[i] = L;
        }
        float biasv[4][4];
        #pragma unroll
        for (int e = 0; e < 4; ++e) {
            int jg = cu * 8 + 4 * hl + e;
            biasv[e][0] = b2x[0 * H_DIM + jg] + b2h[0 * H_DIM + jg];
            biasv[e][1] = b2x[1 * H_DIM + jg] + b2h[1 * H_DIM + jg];
            biasv[e][2] = b2x[2 * H_DIM + jg];
            biasv[e][3] = b2h[2 * H_DIM + jg];
        }
        float hst[4] = {0.f, 0.f, 0.f, 0.f};
        float* cred2 = cred + 2 * 1056;

        for (int s = 0; s <= T_LEN; ++s) {
            if (s >= 1) {   // poll: h1f >= s+1 (h1(s-1)), h2f >= s+1 (h2(s-2))
                const int* fp = (lane < 32) ? &h1f[lane] : &h2f[lane - 32];
                while (true) {
                    int v = __hip_atomic_load(fp, __ATOMIC_RELAXED, __HIP_MEMORY_SCOPE_AGENT);
                    if (__all(v >= s + 1)) break;
                }
            }
            if (lane == 0) lds_st(goG, s + 1);
            unsigned long long hi64 = 0, lo64 = 0;
            if (s >= 1) {
                const char* h2r = gb + 98304 + (s & 1) * 32768;   // h2(s-2)
                short8 hA[16], lA[16];
                #pragma unroll
                for (int i = 0; i < 16; ++i) {
                    hA[i] = ld_frag(h2r + i * 1024 + lane * 16);
                    lA[i] = ld_frag(h2r + 16384 + i * 1024 + lane * 16);
                }
                f32x16 acc0, acc1, acc2, acc3;
                #pragma unroll
                for (int r = 0; r < 16; ++r) { acc0[r]=0.f; acc1[r]=0.f; acc2[r]=0.f; acc3[r]=0.f; }
                #pragma unroll
                for (int i = 0; i < 16; ++i) { f32x16& ac = ACCSEL(i); MFMA3(ac, hA[i], lA[i], BH[i], BL[i]); }
                #pragma unroll
                for (int r = 0; r < 16; ++r) {
                    int b = (r & 3) + 8 * (r >> 2) + 4 * half;
                    cred2[nrow * 33 + b] = acc0[r] + acc1[r] + acc2[r] + acc3[r];
                }
                while (lds_ld(done3) < s) {}
                __threadfence_block();
                #pragma unroll
                for (int e = 0; e < 4; ++e) {
                    int jj = 4 * hl + e;
                    float rc = cred[2112+(jj*4+0)*33+bb] + cred[3168+(jj*4+0)*33+bb] + biasv[e][0];
                    float zc = cred[2112+(jj*4+1)*33+bb] + cred[3168+(jj*4+1)*33+bb] + biasv[e][1];
                    float xn = cred[2112+(jj*4+2)*33+bb] + cred[3168+(jj*4+2)*33+bb] + biasv[e][2];
                    float hn = cred[2112+(jj*4+3)*33+bb] + cred[3168+(jj*4+3)*33+bb] + biasv[e][3];
                    float rg = sigmoidf_(rc), zg = sigmoidf_(zc);
                    float ng = tanhf_fast(xn + rg * hn);
                    hst[e] = zg * hst[e] + (1.f - zg) * ng;
                    if (s < T_LEN) {
                        unsigned short h, l;
                        split2(hst[e], h, l);
                        hi64 |= ((unsigned long long)h) << (16 * e);
                        lo64 |= ((unsigned long long)l) << (16 * e);
                    }
                }
            }
            if (s == T_LEN) {
                #pragma unroll
                for (int e = 0; e < 4; ++e)
                    h2out[(size_t)(grp * 32 + bb) * H_DIM + cu * 8 + 4 * hl + e] = hst[e];
            } else {
                char* h2w = gb + 98304 + ((s + 1) & 1) * 32768;   // h2(s-1) -> parity (s-1)&1
                int off = (cu >> 1) * 1024 + (cu & 1) * 512 + bb * 16 + hl * 8;
                __hip_atomic_store((unsigned long long*)(h2w + off), hi64,
                                   __ATOMIC_RELAXED, __HIP_MEMORY_SCOPE_AGENT);
                __hip_atomic_store((unsigned long long*)(h2w + 16384 + off), lo64,
                                   __ATOMIC_RELAXED, __HIP_MEMORY_SCOPE_AGENT);
                asm volatile("s_waitcnt vmcnt(0)" ::: "memory");
                if (lane == 0)
                    __hip_atomic_store(&h2f[cu], s + 2, __ATOMIC_RELAXED, __HIP_MEMORY_SCOPE_AGENT);
            }
        }
    } else {
        // ================= GRU HELPER: h1-side (w2x rows) -> cred3 ===========
        short8 BH[16], BL[16];
        #pragma unroll
        for (int i = 0; i < 16; ++i) {
            short8 H, L;
            #pragma unroll
            for (int e = 0; e < 8; ++e) {
                int kk = i * 16 + half * 8 + e;
                float v = (q < 3) ? w2x[(q * H_DIM + cu * 8 + jrow) * H_DIM + kk] : 0.f;
                unsigned short hh, ll;
                split2(v, hh, ll);
                H[e] = (short)hh; L[e] = (short)ll;
            }
            BH[i] = H; BL[i] = L;
        }
        float* cred3 = cred + 3 * 1056;
        for (int s = 1; s <= T_LEN; ++s) {
            while (lds_ld(goG) < s + 1) {}
            __threadfence_block();
            const char* h1r = gb + ((s + 2) % 3) * 32768;   // h1(s-1)
            short8 hA[16], lA[16];
            #pragma unroll
            for (int i = 0; i < 16; ++i) {
                hA[i] = ld_frag(h1r + i * 1024 + lane * 16);
                lA[i] = ld_frag(h1r + 16384 + i * 1024 + lane * 16);
            }
            f32x16 acc0, acc1, acc2, acc3;
            #pragma unroll
            for (int r = 0; r < 16; ++r) { acc0[r]=0.f; acc1[r]=0.f; acc2[r]=0.f; acc3[r]=0.f; }
            #pragma unroll
            for (int i = 0; i < 16; ++i) { f32x16& ac = ACCSEL(i); MFMA3(ac, hA[i], lA[i], BH[i], BL[i]); }
            #pragma unroll
            for (int r = 0; r < 16; ++r) {
                int b = (r & 3) + 8 * (r >> 2) + 4 * half;
                cred3[nrow * 33 + b] = acc0[r] + acc1[r] + acc2[r] + acc3[r];
            }
            __threadfence_block();
            if (lane == 0) lds_st(done3, s);
        }
    }
}

// out[b][o] = concat(h_fwd[b], h_bwd[b]) . wo[o] + bo[o]
__global__ __launch_bounds__(128)
void brnn_out(const float* __restrict__ h2out, const float* __restrict__ wo,
              const float* __restrict__ bo, float* __restrict__ out)
{
    __shared__ float hc[512];
    int b = blockIdx.x;
    int o = threadIdx.x;
    int btile = b >> 5, bi = b & 31;
    for (int k = threadIdx.x; k < 256; k += 128) {
        hc[k]       = h2out[((size_t)(btile)     * 32 + bi) * H_DIM + k];
        hc[256 + k] = h2out[((size_t)(4 + btile) * 32 + bi) * H_DIM + k];
    }
    __syncthreads();
    float acc = bo[o];
    const float4* w4 = (const float4*)&wo[(size_t)o * 512];
    #pragma unroll 8
    for (int k = 0; k < 128; ++k) {
        float4 w = w4[k];
        acc += w.x * hc[k * 4] + w.y * hc[k * 4 + 1] + w.z * hc[k * 4 + 2] + w.w * hc[k * 4 + 3];
    }
    out[b * 128 + o] = acc;
}

extern "C" void kernel_launch(void* const* d_in, const int* in_sizes, int n_in,
                              void* d_out, int out_size, void* d_ws, size_t ws_size,
                              hipStream_t stream) {
    const float* x   = (const float*)d_in[0];
    const float* w1x = (const float*)d_in[1];
    const float* b1x = (const float*)d_in[2];
    const float* w1h = (const float*)d_in[3];
    const float* b1h = (const float*)d_in[4];
    const float* w2x = (const float*)d_in[5];
    const float* b2x = (const float*)d_in[6];
    const float* w2h = (const float*)d_in[7];
    const float* b2h = (const float*)d_in[8];
    const float* wo  = (const float*)d_in[9];
    const float* bo  = (const float*)d_in[10];
    float* out = (float*)d_out;

    char* ws = (char*)d_ws;
    int* flags = (int*)ws;                            // 8 grp x 64 ints (h1f, h2f)
    char* exgb = ws + 4096;                           // 8 x 163840 = 1.25MB
    float* h2out = (float*)(ws + 4096 + 8 * 163840);  // 256 x 256 f32 = 256KB

    hipMemsetAsync(flags, 0, 8 * 64 * sizeof(int), stream);

    size_t shmem = LDS_BYTES;
    hipFuncSetAttribute((const void*)brnn_persistent,
                        hipFuncAttributeMaxDynamicSharedMemorySize, (int)shmem);

    void* args[] = { (void*)&x, (void*)&w1x, (void*)&b1x, (void*)&w1h, (void*)&b1h,
                     (void*)&w2x, (void*)&b2x, (void*)&w2h, (void*)&b2h,
                     (void*)&flags, (void*)&exgb, (void*)&h2out };
    hipError_t err = hipLaunchCooperativeKernel((void*)brnn_persistent,
                                                dim3(256), dim3(256), args,
                                                (unsigned int)shmem, stream);
    if (err != hipSuccess) {
        brnn_persistent<<<dim3(256), dim3(256), shmem, stream>>>(
            x, w1x, b1x, w1h, b1h, w2x, b2x, w2h, b2h, flags, exgb, h2out);
    }

    brnn_out<<<dim3(128), dim3(128), 0, stream>>>(h2out, wo, bo, out);
}

// Round 9
// 16108.412 us; speedup vs baseline: 1.1646x; 1.0611x over previous
//
#include <hip/hip_runtime.h>

// Problem constants
#define T_LEN 2048
#define I_DIM 128
#define H_DIM 256

// 8 groups (2 dir x 4 batch-tiles of 32) x 32 CUs; grp = wg & 7, cu = wg >> 3.
// Each CU owns hidden cols [cu*8, cu*8+8).
//
// DECOUPLED PAIRS (both waves of a pair poll & load CONCURRENTLY — R5 shape):
//   LSTM pair (w0,w1): step sigma: x-part MFMA pre-poll; poll {h1f>=sigma+1,
//     h2f>=sigma-1}; h-part MFMA; pair-bar; nonlin(128t); publish h1(sigma)
//     -> slot sigma%3; vmcnt drain; pair-bar; post h1f=sigma+2.
//   GRU pair (w2,w3): step g computes GRU(g-1): poll {h1f>=g+1, h2f>=g};
//     MFMA h1(g-1),h2(g-2); pair-bar; nonlin; publish h2(g-1) -> slot
//     (g+2)%3; stage x(g+2) into LDS slot (g+2)%3; drain; pair-bar; post
//     h2f=g+1; gstep=g+1 (LDS, certifies x staging for own LSTM pair).
// All cross-CU traffic: RELAXED agent atomics only (R3/R5-proven).
// h1, h2, x: TRIPLE-buffered (peer skew <= 1 step audited).
//
// Exchange per group (196608 B): h1 slot k at k*32768 (hi 16K, lo +16384);
// h2 slot k at 98304 + k*32768. Slice layout: [2 khalf][32 b][8 e] bf16;
// lane*16 = mfma_32x32x16 A-frag.

// LDS offsets (bytes)
#define XB(p)    ((p) * 16384)      // 3 x-bufs: hi 8KB + lo 8KB each
#define CRED_OFF 49152              // 4 x 1056 f32 = 16896
#define CTR_OFF  66048              // barL, barG, gstep @ 64B apart
#define LDS_BYTES 98304             // oversized: forces 1 WG/CU

typedef __attribute__((ext_vector_type(8))) short short8;
typedef __attribute__((ext_vector_type(16))) float f32x16;

__device__ __forceinline__ float sigmoidf_(float v) { return 1.f / (1.f + __expf(-v)); }
__device__ __forceinline__ float tanhf_fast(float v) {
    float t = __expf(-2.f * fabsf(v));
    float r = (1.f - t) / (1.f + t);
    return v < 0.f ? -r : r;
}
__device__ __forceinline__ unsigned short bf16_rne(float f) {
    unsigned u = __float_as_uint(f);
    return (unsigned short)((u + 0x7fffu + ((u >> 16) & 1u)) >> 16);
}
__device__ __forceinline__ void split2(float a, unsigned short& h, unsigned short& l) {
    h = bf16_rne(a);
    float hf = __uint_as_float(((unsigned)h) << 16);
    l = bf16_rne(a - hf);
}
// 16B A-frag as two relaxed agent-scope u64 loads (R3/R5-proven coherence)
__device__ __forceinline__ short8 ld_frag(const char* p) {
    union { unsigned long long u[2]; short8 s; } v;
    v.u[0] = __hip_atomic_load((const unsigned long long*)p,
                               __ATOMIC_RELAXED, __HIP_MEMORY_SCOPE_AGENT);
    v.u[1] = __hip_atomic_load((const unsigned long long*)(p + 8),
                               __ATOMIC_RELAXED, __HIP_MEMORY_SCOPE_AGENT);
    return v.s;
}
__device__ __forceinline__ int lds_ld(const int* c) {
    return __hip_atomic_load(c, __ATOMIC_RELAXED, __HIP_MEMORY_SCOPE_WORKGROUP);
}
__device__ __forceinline__ void lds_st(int* c, int v) {
    __hip_atomic_store(c, v, __ATOMIC_RELAXED, __HIP_MEMORY_SCOPE_WORKGROUP);
}
// Monotone LDS pair barrier (128 arrivals per instance).
__device__ __forceinline__ void pair_bar(int* c, int target) {
    __threadfence_block();
    __hip_atomic_fetch_add(c, 1, __ATOMIC_RELAXED, __HIP_MEMORY_SCOPE_WORKGROUP);
    while (__hip_atomic_load(c, __ATOMIC_RELAXED, __HIP_MEMORY_SCOPE_WORKGROUP) < target) {}
    __threadfence_block();
}
// 64-lane gather poll on split flags (lanes<32: set1, lanes>=32: set2)
__device__ __forceinline__ void poll2(const int* base, int lane, int t1, int t2) {
    const int* fp = base + ((lane < 32) ? lane : (lane + 32));
    int tgt = (lane < 32) ? t1 : t2;
    while (true) {
        int v = __hip_atomic_load(fp, __ATOMIC_RELAXED, __HIP_MEMORY_SCOPE_AGENT);
        if (__all(v >= tgt)) break;
    }
}

__device__ __forceinline__ void stage_unit(const float* __restrict__ x, char* hi, char* lo,
                                           int b0, int teff, int b, int cq) {
    const float4* src = (const float4*)(x + ((size_t)(b0 + b) * T_LEN + teff) * I_DIM + cq * 16);
    float4 v0 = src[0], v1 = src[1], v2 = src[2], v3 = src[3];
    float f[16] = {v0.x, v0.y, v0.z, v0.w, v1.x, v1.y, v1.z, v1.w,
                   v2.x, v2.y, v2.z, v2.w, v3.x, v3.y, v3.z, v3.w};
    short8 H0, H1, L0, L1;
    #pragma unroll
    for (int e = 0; e < 8; ++e) {
        unsigned short h, l;
        split2(f[e], h, l);      H0[e] = (short)h; L0[e] = (short)l;
        split2(f[8 + e], h, l);  H1[e] = (short)h; L1[e] = (short)l;
    }
    char* bh = hi + cq * 1024 + b * 16;
    char* bl = lo + cq * 1024 + b * 16;
    *(short8*)bh = H0; *(short8*)(bh + 512) = H1;
    *(short8*)bl = L0; *(short8*)(bl + 512) = L1;
}

#define MFMA3(ac, ah, al, bh, bl)                                              \
    ac = __builtin_amdgcn_mfma_f32_32x32x16_bf16(ah, bh, ac, 0, 0, 0);         \
    ac = __builtin_amdgcn_mfma_f32_32x32x16_bf16(ah, bl, ac, 0, 0, 0);         \
    ac = __builtin_amdgcn_mfma_f32_32x32x16_bf16(al, bh, ac, 0, 0, 0);

#define ACCSEL(i) ((i & 3) == 0 ? acc0 : (i & 3) == 1 ? acc1 : (i & 3) == 2 ? acc2 : acc3)

__global__ __launch_bounds__(256, 1)
void brnn_persistent(const float* __restrict__ x,
                     const float* __restrict__ w1x, const float* __restrict__ b1x,
                     const float* __restrict__ w1h, const float* __restrict__ b1h,
                     const float* __restrict__ w2x, const float* __restrict__ b2x,
                     const float* __restrict__ w2h, const float* __restrict__ b2h,
                     int* flags, char* exgb, float* h2out)
{
    extern __shared__ char smem_b[];

    const int tid  = threadIdx.x;
    const int lane = tid & 63;
    const int wid  = tid >> 6;
    const int wg   = blockIdx.x;
    const int grp  = wg & 7;
    const int cu   = wg >> 3;
    const int dir  = grp >> 2;
    const int btile = grp & 3;
    const int b0   = btile * 32;

    char* gb = exgb + (size_t)grp * 196608;
    int* h1f = flags + grp * 128;       // [32] at +0
    int* h2f = h1f + 64;                // [32] at +64 (separate lines)
    int* barL  = (int*)(smem_b + CTR_OFF);
    int* barG  = (int*)(smem_b + CTR_OFF + 64);
    int* gstep = (int*)(smem_b + CTR_OFF + 128);
    float* cred = (float*)(smem_b + CRED_OFF);

    const int nrow = lane & 31;        // output row within 32-row tile
    const int jrow = nrow >> 2;
    const int q    = nrow & 3;
    const int half = lane >> 5;
    // nonlin owner coords (within each pair's 128 threads)
    const int tt  = (tid < 128) ? tid : (tid - 128);
    const int bbn = tt & 31;
    const int qn  = tt >> 5;           // 0..3; states j = 2*qn+{0,1}

    // ---------------- B-fragment preload (weights -> VGPRs, bf16 hi/lo) ------
    // w0: x slices 0-3 + h1 slices 0-7; w1: x slices 4-7 + h1 slices 8-15
    // w2: GRU w2x rows (r,z,n,0) x h1; w3: GRU w2h rows (r,z,0,n) x h2
    short8 BH[16], BL[16];
    #pragma unroll
    for (int i = 0; i < 16; ++i) {
        short8 H, L;
        #pragma unroll
        for (int e = 0; e < 8; ++e) {
            float v = 0.f;
            if (wid < 2) {
                if (i < 12) {
                    int k = (i < 4) ? ((wid * 4 + i) * 16 + half * 8 + e)
                                    : (128 + (wid * 8 + (i - 4)) * 16 + half * 8 + e);
                    int R = q * H_DIM + cu * 8 + jrow;
                    v = (k < I_DIM) ? w1x[R * I_DIM + k] : w1h[R * H_DIM + (k - I_DIM)];
                }
            } else if (wid == 2) {
                int kk = i * 16 + half * 8 + e;
                if (q < 3) v = w2x[(q * H_DIM + cu * 8 + jrow) * H_DIM + kk];
            } else {
                int kk = i * 16 + half * 8 + e;
                if (q == 0)      v = w2h[(0 * H_DIM + cu * 8 + jrow) * H_DIM + kk];
                else if (q == 1) v = w2h[(1 * H_DIM + cu * 8 + jrow) * H_DIM + kk];
                else if (q == 3) v = w2h[(2 * H_DIM + cu * 8 + jrow) * H_DIM + kk];
            }
            unsigned short hh, ll;
            split2(v, hh, ll);
            H[e] = (short)hh; L[e] = (short)ll;
        }
        BH[i] = H; BL[i] = L;
    }

    // ---------------- bias constants (per pair) ------------------------------
    float biasA[2][4];
    #pragma unroll
    for (int e = 0; e < 2; ++e) {
        int jg = cu * 8 + 2 * qn + e;
        if (tid < 128) {
            #pragma unroll
            for (int g = 0; g < 4; ++g)
                biasA[e][g] = b1x[g * H_DIM + jg] + b1h[g * H_DIM + jg];
        } else {
            biasA[e][0] = b2x[0 * H_DIM + jg] + b2h[0 * H_DIM + jg];
            biasA[e][1] = b2x[1 * H_DIM + jg] + b2h[1 * H_DIM + jg];
            biasA[e][2] = b2x[2 * H_DIM + jg];
            biasA[e][3] = b2h[2 * H_DIM + jg];
        }
    }
    float st[2] = {0.f, 0.f};          // c-state (LSTM pair) / h2-state (GRU pair)

    // ---------------- init ---------------------------------------------------
    if (tid < 3) lds_st((int*)(smem_b + CTR_OFF + tid * 64), 0);
    if (tid < 128) {   // zero own slice of h1(-1) = slot 2, both planes
        char* p2 = gb + 2 * 32768 + ((tid >> 6) ? 16384 : 0)
                 + (cu >> 1) * 1024 + (cu & 1) * 512 + (tid & 63) * 8;
        __hip_atomic_store((unsigned long long*)p2, 0ull,
                           __ATOMIC_RELAXED, __HIP_MEMORY_SCOPE_AGENT);
    }
    // stage x(0) -> slot 0, x(1) -> slot 1 (all 256 threads, 1 unit each)
    stage_unit(x, smem_b + XB(0), smem_b + XB(0) + 8192, b0,
               dir ? (T_LEN - 1) : 0, tid >> 3, tid & 7);
    stage_unit(x, smem_b + XB(1), smem_b + XB(1) + 8192, b0,
               dir ? (T_LEN - 2) : 1, tid >> 3, tid & 7);
    asm volatile("s_waitcnt vmcnt(0)" ::: "memory");
    __syncthreads();   // only workgroup barrier in the kernel
    if (tid == 0) __hip_atomic_store(&h1f[cu], 1, __ATOMIC_RELAXED, __HIP_MEMORY_SCOPE_AGENT);

    if (wid < 2) {
        // ===================== LSTM PAIR (w0, w1) ============================
        for (int s = 0; s < T_LEN; ++s) {
            // x(s) staging certification (own GRU pair staged it at step s-2)
            while (lds_ld(gstep) < s - 1) {}
            __threadfence_block();
            // x-part MFMA (pre-poll; x LDS-local)
            f32x16 acc0, acc1, acc2, acc3;
            #pragma unroll
            for (int r = 0; r < 16; ++r) { acc0[r]=0.f; acc1[r]=0.f; acc2[r]=0.f; acc3[r]=0.f; }
            {
                const char* xh = smem_b + XB(s % 3);
                const char* xl = xh + 8192;
                #pragma unroll
                for (int i = 0; i < 4; ++i) {
                    short8 ah = *(const short8*)(xh + (wid * 4 + i) * 1024 + lane * 16);
                    short8 al = *(const short8*)(xl + (wid * 4 + i) * 1024 + lane * 16);
                    f32x16& ac = ACCSEL(i);
                    MFMA3(ac, ah, al, BH[i], BL[i]);
                }
            }
            // poll: data h1(s-1) ready; guard: peers' GRU(s-3) done (h1 slot safe)
            poll2(h1f, lane, s + 1, s - 1);
            // h-part: 8 slices/wave from h1 slot (s+2)%3
            {
                const char* h1r = gb + ((s + 2) % 3) * 32768;
                short8 hA[8], lA[8];
                #pragma unroll
                for (int i = 0; i < 8; ++i) {
                    hA[i] = ld_frag(h1r + (wid * 8 + i) * 1024 + lane * 16);
                    lA[i] = ld_frag(h1r + 16384 + (wid * 8 + i) * 1024 + lane * 16);
                }
                #pragma unroll
                for (int i = 0; i < 8; ++i) {
                    f32x16& ac = ACCSEL(4 + i);
                    MFMA3(ac, hA[i], lA[i], BH[4 + i], BL[4 + i]);
                }
            }
            {
                float* credw = cred + wid * 1056;
                #pragma unroll
                for (int r = 0; r < 16; ++r) {
                    int b = (r & 3) + 8 * (r >> 2) + 4 * half;
                    credw[nrow * 33 + b] = acc0[r] + acc1[r] + acc2[r] + acc3[r];
                }
            }
            pair_bar(barL, 128 * (2 * s + 1));
            // nonlin (128 threads of the pair), publish h1(s) -> slot s%3
            {
                unsigned hi32 = 0, lo32 = 0;
                #pragma unroll
                for (int e = 0; e < 2; ++e) {
                    int jj = 2 * qn + e;
                    float gi = cred[(jj*4+0)*33+bbn] + cred[1056+(jj*4+0)*33+bbn] + biasA[e][0];
                    float gf = cred[(jj*4+1)*33+bbn] + cred[1056+(jj*4+1)*33+bbn] + biasA[e][1];
                    float gg = cred[(jj*4+2)*33+bbn] + cred[1056+(jj*4+2)*33+bbn] + biasA[e][2];
                    float go = cred[(jj*4+3)*33+bbn] + cred[1056+(jj*4+3)*33+bbn] + biasA[e][3];
                    float ig = sigmoidf_(gi), fg = sigmoidf_(gf);
                    float cg = tanhf_fast(gg), og = sigmoidf_(go);
                    st[e] = st[e] * fg + ig * cg;
                    float h1v = og * tanhf_fast(st[e]);
                    unsigned short h, l;
                    split2(h1v, h, l);
                    hi32 |= ((unsigned)h) << (16 * e);
                    lo32 |= ((unsigned)l) << (16 * e);
                }
                char* h1w = gb + (s % 3) * 32768;
                int off = (cu >> 1) * 1024 + (cu & 1) * 512 + bbn * 16 + qn * 4;
                __hip_atomic_store((unsigned*)(h1w + off), hi32,
                                   __ATOMIC_RELAXED, __HIP_MEMORY_SCOPE_AGENT);
                __hip_atomic_store((unsigned*)(h1w + 16384 + off), lo32,
                                   __ATOMIC_RELAXED, __HIP_MEMORY_SCOPE_AGENT);
            }
            asm volatile("s_waitcnt vmcnt(0)" ::: "memory");
            pair_bar(barL, 128 * (2 * s + 2));
            if (tid == 0)
                __hip_atomic_store(&h1f[cu], s + 2, __ATOMIC_RELAXED, __HIP_MEMORY_SCOPE_AGENT);
        }
    } else {
        // ===================== GRU PAIR (w2, w3) =============================
        for (int g = 0; g <= T_LEN; ++g) {
            unsigned hi32 = 0, lo32 = 0;
            if (g >= 1) {
                // poll: h1(g-1) ready (h1f>=g+1); h2(g-2) ready (h2f>=g)
                poll2(h1f, lane, g + 1, g);
                const char* srcb = (wid == 2) ? (gb + ((g + 2) % 3) * 32768)            // h1(g-1)
                                              : (gb + 98304 + ((g + 1) % 3) * 32768);   // h2(g-2)
                short8 hA[16], lA[16];
                #pragma unroll
                for (int i = 0; i < 16; ++i) {
                    hA[i] = ld_frag(srcb + i * 1024 + lane * 16);
                    lA[i] = ld_frag(srcb + 16384 + i * 1024 + lane * 16);
                }
                f32x16 acc0, acc1, acc2, acc3;
                #pragma unroll
                for (int r = 0; r < 16; ++r) { acc0[r]=0.f; acc1[r]=0.f; acc2[r]=0.f; acc3[r]=0.f; }
                #pragma unroll
                for (int i = 0; i < 16; ++i) {
                    f32x16& ac = ACCSEL(i);
                    MFMA3(ac, hA[i], lA[i], BH[i], BL[i]);
                }
                {
                    float* credw = cred + wid * 1056;
                    #pragma unroll
                    for (int r = 0; r < 16; ++r) {
                        int b = (r & 3) + 8 * (r >> 2) + 4 * half;
                        credw[nrow * 33 + b] = acc0[r] + acc1[r] + acc2[r] + acc3[r];
                    }
                }
                pair_bar(barG, 128 * (2 * g));
                // nonlin (128 threads of the pair)
                #pragma unroll
                for (int e = 0; e < 2; ++e) {
                    int jj = 2 * qn + e;
                    float rc = cred[2112+(jj*4+0)*33+bbn] + cred[3168+(jj*4+0)*33+bbn] + biasA[e][0];
                    float zc = cred[2112+(jj*4+1)*33+bbn] + cred[3168+(jj*4+1)*33+bbn] + biasA[e][1];
                    float xn = cred[2112+(jj*4+2)*33+bbn] + cred[3168+(jj*4+2)*33+bbn] + biasA[e][2];
                    float hn = cred[2112+(jj*4+3)*33+bbn] + cred[3168+(jj*4+3)*33+bbn] + biasA[e][3];
                    float rg = sigmoidf_(rc), zg = sigmoidf_(zc);
                    float ng = tanhf_fast(xn + rg * hn);
                    st[e] = zg * st[e] + (1.f - zg) * ng;
                    unsigned short h, l;
                    split2(st[e], h, l);
                    hi32 |= ((unsigned)h) << (16 * e);
                    lo32 |= ((unsigned)l) << (16 * e);
                }
            }
            if (g == T_LEN) {   // final: h2(T-1) -> output
                #pragma unroll
                for (int e = 0; e < 2; ++e)
                    h2out[(size_t)(grp * 32 + bbn) * H_DIM + cu * 8 + 2 * qn + e] = st[e];
                break;
            }
            // publish h2(g-1) -> slot (g+2)%3 (zeros for g==0)
            {
                char* h2w = gb + 98304 + ((g + 2) % 3) * 32768;
                int off = (cu >> 1) * 1024 + (cu & 1) * 512 + bbn * 16 + qn * 4;
                __hip_atomic_store((unsigned*)(h2w + off), hi32,
                                   __ATOMIC_RELAXED, __HIP_MEMORY_SCOPE_AGENT);
                __hip_atomic_store((unsigned*)(h2w + 16384 + off), lo32,
                                   __ATOMIC_RELAXED, __HIP_MEMORY_SCOPE_AGENT);
            }
            // stage x(g+2) -> LDS slot (g+2)%3 (consumed by own LSTM at step g+2)
            if (g + 2 <= T_LEN - 1) {
                int teff = dir ? (T_LEN - 1 - (g + 2)) : (g + 2);
                char* nxh = smem_b + XB((g + 2) % 3);
                char* nxl = nxh + 8192;
                int t2 = tid - 128;
                #pragma unroll
                for (int i = 0; i < 2; ++i) {
                    int u = t2 * 2 + i;
                    stage_unit(x, nxh, nxl, b0, teff, u >> 3, u & 7);
                }
            }
            asm volatile("s_waitcnt vmcnt(0) lgkmcnt(0)" ::: "memory");
            pair_bar(barG, 128 * (2 * g + 1));
            if (tid == 128) {
                __hip_atomic_store(&h2f[cu], g + 1, __ATOMIC_RELAXED, __HIP_MEMORY_SCOPE_AGENT);
                lds_st(gstep, g + 1);
            }
        }
    }
}

// out[b][o] = concat(h_fwd[b], h_bwd[b]) . wo[o] + bo[o]
__global__ __launch_bounds__(128)
void brnn_out(const float* __restrict__ h2out, const float* __restrict__ wo,
              const float* __restrict__ bo, float* __restrict__ out)
{
    __shared__ float hc[512];
    int b = blockIdx.x;
    int o = threadIdx.x;
    int btile = b >> 5, bi = b & 31;
    for (int k = threadIdx.x; k < 256; k += 128) {
        hc[k]       = h2out[((size_t)(btile)     * 32 + bi) * H_DIM + k];
        hc[256 + k] = h2out[((size_t)(4 + btile) * 32 + bi) * H_DIM + k];
    }
    __syncthreads();
    float acc = bo[o];
    const float4* w4 = (const float4*)&wo[(size_t)o * 512];
    #pragma unroll 8
    for (int k = 0; k < 128; ++k) {
        float4 w = w4[k];
        acc += w.x * hc[k * 4] + w.y * hc[k * 4 + 1] + w.z * hc[k * 4 + 2] + w.w * hc[k * 4 + 3];
    }
    out[b * 128 + o] = acc;
}

extern "C" void kernel_launch(void* const* d_in, const int* in_sizes, int n_in,
                              void* d_out, int out_size, void* d_ws, size_t ws_size,
                              hipStream_t stream) {
    const float* x   = (const float*)d_in[0];
    const float* w1x = (const float*)d_in[1];
    const float* b1x = (const float*)d_in[2];
    const float* w1h = (const float*)d_in[3];
    const float* b1h = (const float*)d_in[4];
    const float* w2x = (const float*)d_in[5];
    const float* b2x = (const float*)d_in[6];
    const float* w2h = (const float*)d_in[7];
    const float* b2h = (const float*)d_in[8];
    const float* wo  = (const float*)d_in[9];
    const float* bo  = (const float*)d_in[10];
    float* out = (float*)d_out;

    char* ws = (char*)d_ws;
    int* flags = (int*)ws;                              // 8 grp x 128 ints
    char* exgb = ws + 8192;                             // 8 x 196608 = 1.5MB
    float* h2out = (float*)(ws + 8192 + 8 * 196608);    // 256 x 256 f32 = 256KB

    hipMemsetAsync(flags, 0, 8 * 128 * sizeof(int), stream);

    size_t shmem = LDS_BYTES;
    hipFuncSetAttribute((const void*)brnn_persistent,
                        hipFuncAttributeMaxDynamicSharedMemorySize, (int)shmem);

    void* args[] = { (void*)&x, (void*)&w1x, (void*)&b1x, (void*)&w1h, (void*)&b1h,
                     (void*)&w2x, (void*)&b2x, (void*)&w2h, (void*)&b2h,
                     (void*)&flags, (void*)&exgb, (void*)&h2out };
    hipError_t err = hipLaunchCooperativeKernel((void*)brnn_persistent,
                                                dim3(256), dim3(256), args,
                                                (unsigned int)shmem, stream);
    if (err != hipSuccess) {
        brnn_persistent<<<dim3(256), dim3(256), shmem, stream>>>(
            x, w1x, b1x, w1h, b1h, w2x, b2x, w2h, b2h, flags, exgb, h2out);
    }

    brnn_out<<<dim3(128), dim3(128), 0, stream>>>(h2out, wo, bo, out);
}

// Round 10
// 13757.854 us; speedup vs baseline: 1.3635x; 1.1709x over previous
//
#include <hip/hip_runtime.h>

// Problem constants
#define T_LEN 2048
#define I_DIM 128
#define H_DIM 256

// 8 groups (2 dir x 4 batch-tiles of 32) x 32 CUs; grp = wg & 7, cu = wg >> 3.
// Each CU owns hidden cols [cu*8, cu*8+8).
//
// R5's COUPLED schedule (proven best): step s computes LSTM(s) [s<T] and
// GRU(s-1) [s>=1]; ONE sync round per step. Improvements over R5:
//  - dual-use h1 frags (one load feeds LSTM-h and GRU-x MFMA): 48 -> 32 pairs/CU
//  - balanced loads (max 16 pairs/wave), single batch -> one LLC RTT
//  - direct nonlin publish (no hstage LDS pass), 1 barrier/step (was 4)
//  - per-CU flag = counter; each wave vmcnt(0)+fetch_add(1); poll >= 4(s+1)
// Coherence: RELAXED agent-scope atomics only (R3/R5-proven; no fences).
//
// Wave roles: w0 = LSTM x-part (LDS) + x stager; w1 = h1 slices 0..7
// (LSTM K128..255 + GRUx K0..127); w2 = h1 slices 8..15 (LSTM K256..383 +
// GRUx K128..255); w3 = h2 slices 0..15 (GRUh K0..255).
// cred: c0=w0 LSTM, c1=w1 LSTM, c2=w2 LSTM, c3=w1 GRUx, c4=w2 GRUx, c5=w3 GRUh.
//
// Exchange per (parity, group): 64KB = hi [32 slices][1024B] at +0, lo at
// +32768. Slices 0..15 = h1, 16..31 = h2. Slice: [2 half][32 b][8 e] bf16;
// lane*16 = mfma_32x32x16 A-frag. Write parity s&1, read parity (s+1)&1.

// LDS offsets (bytes)
#define XHI_OFF 0               // x slices 0..7: 8KB
#define XLO_OFF 8192            // 8KB
#define CRED_OFF 16384          // 6 x 1056 f32 = 25344
#define LDS_BYTES 98304         // oversized: forces 1 WG/CU

typedef __attribute__((ext_vector_type(8))) short short8;
typedef __attribute__((ext_vector_type(16))) float f32x16;

__device__ __forceinline__ float sigmoidf_(float v) { return 1.f / (1.f + __expf(-v)); }
__device__ __forceinline__ float tanhf_fast(float v) {
    float t = __expf(-2.f * fabsf(v));
    float r = (1.f - t) / (1.f + t);
    return v < 0.f ? -r : r;
}
__device__ __forceinline__ unsigned short bf16_rne(float f) {
    unsigned u = __float_as_uint(f);
    return (unsigned short)((u + 0x7fffu + ((u >> 16) & 1u)) >> 16);
}
__device__ __forceinline__ void split2(float a, unsigned short& h, unsigned short& l) {
    h = bf16_rne(a);
    float hf = __uint_as_float(((unsigned)h) << 16);
    l = bf16_rne(a - hf);
}
// 16B A-frag as two relaxed agent-scope u64 loads (R3/R5-proven coherence)
__device__ __forceinline__ short8 ld_frag(const char* p) {
    union { unsigned long long u[2]; short8 s; } v;
    v.u[0] = __hip_atomic_load((const unsigned long long*)p,
                               __ATOMIC_RELAXED, __HIP_MEMORY_SCOPE_AGENT);
    v.u[1] = __hip_atomic_load((const unsigned long long*)(p + 8),
                               __ATOMIC_RELAXED, __HIP_MEMORY_SCOPE_AGENT);
    return v.s;
}

__device__ __forceinline__ void stage_unit(const float* __restrict__ x, char* smem_b,
                                           int b0, int teff, int b, int cq) {
    const float4* src = (const float4*)(x + ((size_t)(b0 + b) * T_LEN + teff) * I_DIM + cq * 16);
    float4 v0 = src[0], v1 = src[1], v2 = src[2], v3 = src[3];
    float f[16] = {v0.x, v0.y, v0.z, v0.w, v1.x, v1.y, v1.z, v1.w,
                   v2.x, v2.y, v2.z, v2.w, v3.x, v3.y, v3.z, v3.w};
    short8 H0, H1, L0, L1;
    #pragma unroll
    for (int e = 0; e < 8; ++e) {
        unsigned short h, l;
        split2(f[e], h, l);      H0[e] = (short)h; L0[e] = (short)l;
        split2(f[8 + e], h, l);  H1[e] = (short)h; L1[e] = (short)l;
    }
    char* bh = smem_b + XHI_OFF + cq * 1024 + b * 16;
    char* bl = smem_b + XLO_OFF + cq * 1024 + b * 16;
    *(short8*)bh = H0; *(short8*)(bh + 512) = H1;
    *(short8*)bl = L0; *(short8*)(bl + 512) = L1;
}

#define MFMA3(ac, ah, al, bh, bl)                                              \
    ac = __builtin_amdgcn_mfma_f32_32x32x16_bf16(ah, bh, ac, 0, 0, 0);         \
    ac = __builtin_amdgcn_mfma_f32_32x32x16_bf16(ah, bl, ac, 0, 0, 0);         \
    ac = __builtin_amdgcn_mfma_f32_32x32x16_bf16(al, bh, ac, 0, 0, 0);

#define ACCSEL(i) ((i & 3) == 0 ? acc0 : (i & 3) == 1 ? acc1 : (i & 3) == 2 ? acc2 : acc3)

__global__ __launch_bounds__(256, 1)
void brnn_persistent(const float* __restrict__ x,
                     const float* __restrict__ w1x, const float* __restrict__ b1x,
                     const float* __restrict__ w1h, const float* __restrict__ b1h,
                     const float* __restrict__ w2x, const float* __restrict__ b2x,
                     const float* __restrict__ w2h, const float* __restrict__ b2h,
                     int* flags, char* exgb, float* h2out)
{
    extern __shared__ char smem_b[];

    const int tid  = threadIdx.x;
    const int lane = tid & 63;
    const int wid  = tid >> 6;
    const int wg   = blockIdx.x;
    const int grp  = wg & 7;
    const int cu   = wg >> 3;
    const int dir  = grp >> 2;
    const int btile = grp & 3;
    const int b0   = btile * 32;

    int* flg = flags + grp * 64;       // 32 packed counters per group
    float* cred = (float*)(smem_b + CRED_OFF);

    const int nrow = lane & 31;        // output row n = jrow*4 + q
    const int jrow = nrow >> 2;
    const int q    = nrow & 3;
    const int half = lane >> 5;

    // ---------------- B-fragment preload (weights -> VGPRs, bf16 hi/lo) ------
    short8 BH[16], BL[16];
    #pragma unroll
    for (int i = 0; i < 16; ++i) {
        short8 H, L;
        #pragma unroll
        for (int e = 0; e < 8; ++e) {
            int kk = (i & 7) * 16 + half * 8 + e;   // within-8-slice column
            float v = 0.f;
            if (wid == 0) {
                if (i < 8) {   // x part: K 0..127
                    int R = q * H_DIM + cu * 8 + jrow;
                    v = w1x[R * I_DIM + kk];
                }
            } else if (wid == 1) {
                int R = q * H_DIM + cu * 8 + jrow;
                if (i < 8) v = w1h[R * H_DIM + kk];                         // LSTM K128..255
                else if (q < 3) v = w2x[(q * H_DIM + cu * 8 + jrow) * H_DIM + kk]; // GRUx K0..127
            } else if (wid == 2) {
                int R = q * H_DIM + cu * 8 + jrow;
                if (i < 8) v = w1h[R * H_DIM + 128 + kk];                   // LSTM K256..383
                else if (q < 3) v = w2x[(q * H_DIM + cu * 8 + jrow) * H_DIM + 128 + kk];
            } else {
                int kk16 = i * 16 + half * 8 + e;   // 0..255
                if (q == 0)      v = w2h[(0 * H_DIM + cu * 8 + jrow) * H_DIM + kk16];
                else if (q == 1) v = w2h[(1 * H_DIM + cu * 8 + jrow) * H_DIM + kk16];
                else if (q == 3) v = w2h[(2 * H_DIM + cu * 8 + jrow) * H_DIM + kk16];
            }
            unsigned short hh, ll;
            split2(v, hh, ll);
            H[e] = (short)hh; L[e] = (short)ll;
        }
        BH[i] = H; BL[i] = L;
    }

    // ---------------- nonlin-owner constants (2 states per thread) ------------
    // threads 0..127: LSTM (c-state); threads 128..255: GRU (h2-state)
    const int tt  = tid & 127;
    const int bbn = tt & 31;
    const int qn  = tt >> 5;           // 0..3; j = 2*qn + e
    float biasA[2][4];
    #pragma unroll
    for (int e = 0; e < 2; ++e) {
        int jg = cu * 8 + 2 * qn + e;
        if (tid < 128) {
            #pragma unroll
            for (int g = 0; g < 4; ++g)
                biasA[e][g] = b1x[g * H_DIM + jg] + b1h[g * H_DIM + jg];
        } else {
            biasA[e][0] = b2x[0 * H_DIM + jg] + b2h[0 * H_DIM + jg];
            biasA[e][1] = b2x[1 * H_DIM + jg] + b2h[1 * H_DIM + jg];
            biasA[e][2] = b2x[2 * H_DIM + jg];
            biasA[e][3] = b2h[2 * H_DIM + jg];
        }
    }
    float st[2] = {0.f, 0.f};

    // ---------------- init ---------------------------------------------------
    if (tid < 128) {   // zero own h1(-1) slice region in parity-1, both planes
        char* p1 = exgb + (size_t)(8 + grp) * 65536 + (tid >> 6) * 32768
                 + (cu >> 1) * 1024 + (cu & 1) * 512 + (tid & 63) * 8;
        __hip_atomic_store((unsigned long long*)p1, 0ull,
                           __ATOMIC_RELAXED, __HIP_MEMORY_SCOPE_AGENT);
    }
    stage_unit(x, smem_b, b0, dir ? (T_LEN - 1) : 0, tid >> 3, tid & 7);
    __syncthreads();   // drains init stores (vmcnt) + LDS
    if (tid == 0)
        __hip_atomic_store(&flg[cu], 4, __ATOMIC_RELAXED, __HIP_MEMORY_SCOPE_AGENT);

    for (int s = 0; s <= T_LEN; ++s) {
        // ---------------- poll (every wave, all 32 CU counters) --------------
        {
            int tgt = 4 * (s + 1);
            const int* fp = &flg[lane & 31];
            while (true) {
                int v = (lane < 32)
                    ? __hip_atomic_load(fp, __ATOMIC_RELAXED, __HIP_MEMORY_SCOPE_AGENT)
                    : 0x7fffffff;
                if (__all(v >= tgt)) break;
            }
        }
        const char* exR = exgb + (size_t)(((s + 1) & 1) * 8 + grp) * 65536;
        char*       exW = exgb + (size_t)(((s)     & 1) * 8 + grp) * 65536;

        // ---------------- MFMA phase (single-batch loads) --------------------
        f32x16 acc0, acc1, acc2, acc3;
        #pragma unroll
        for (int r = 0; r < 16; ++r) { acc0[r]=0.f; acc1[r]=0.f; acc2[r]=0.f; acc3[r]=0.f; }

        if (wid == 0) {
            if (s < T_LEN) {
                #pragma unroll
                for (int i = 0; i < 8; ++i) {
                    short8 ah = *(const short8*)(smem_b + XHI_OFF + i * 1024 + lane * 16);
                    short8 al = *(const short8*)(smem_b + XLO_OFF + i * 1024 + lane * 16);
                    f32x16& ac = ACCSEL(i);
                    MFMA3(ac, ah, al, BH[i], BL[i]);
                }
                float* c0 = cred;
                #pragma unroll
                for (int r = 0; r < 16; ++r) {
                    int b = (r & 3) + 8 * (r >> 2) + 4 * half;
                    c0[nrow * 33 + b] = acc0[r] + acc1[r] + acc2[r] + acc3[r];
                }
            }
        } else if (wid < 3) {
            const int sb = (wid == 1) ? 0 : 8;
            short8 hA[8], lA[8];
            #pragma unroll
            for (int i = 0; i < 8; ++i) {
                hA[i] = ld_frag(exR + (sb + i) * 1024 + lane * 16);
                lA[i] = ld_frag(exR + 32768 + (sb + i) * 1024 + lane * 16);
            }
            if (s < T_LEN) {   // LSTM part (dual-use A)
                #pragma unroll
                for (int i = 0; i < 8; ++i) {
                    f32x16& ac = (i & 1) ? acc1 : acc0;
                    MFMA3(ac, hA[i], lA[i], BH[i], BL[i]);
                }
            }
            if (s >= 1) {      // GRUx part (same A, different B)
                #pragma unroll
                for (int i = 0; i < 8; ++i) {
                    f32x16& ac = (i & 1) ? acc3 : acc2;
                    MFMA3(ac, hA[i], lA[i], BH[8 + i], BL[8 + i]);
                }
            }
            float* cL = cred + wid * 1056;          // c1 / c2
            float* cX = cred + (2 + wid) * 1056;    // c3 / c4
            #pragma unroll
            for (int r = 0; r < 16; ++r) {
                int b = (r & 3) + 8 * (r >> 2) + 4 * half;
                cL[nrow * 33 + b] = acc0[r] + acc1[r];
                cX[nrow * 33 + b] = acc2[r] + acc3[r];
            }
        } else {
            if (s >= 1) {
                short8 hA[16], lA[16];
                #pragma unroll
                for (int i = 0; i < 16; ++i) {
                    hA[i] = ld_frag(exR + (16 + i) * 1024 + lane * 16);
                    lA[i] = ld_frag(exR + 32768 + (16 + i) * 1024 + lane * 16);
                }
                #pragma unroll
                for (int i = 0; i < 16; ++i) {
                    f32x16& ac = ACCSEL(i);
                    MFMA3(ac, hA[i], lA[i], BH[i], BL[i]);
                }
                float* c5 = cred + 5 * 1056;
                #pragma unroll
                for (int r = 0; r < 16; ++r) {
                    int b = (r & 3) + 8 * (r >> 2) + 4 * half;
                    c5[nrow * 33 + b] = acc0[r] + acc1[r] + acc2[r] + acc3[r];
                }
            }
        }
        __syncthreads();   // the ONE barrier: cred complete before nonlin

        // ---------------- nonlin + direct publish ----------------------------
        if (tid < 128) {
            if (s < T_LEN) {   // LSTM: 2 states, publish h1(s) as u32 pairs
                unsigned hi32 = 0, lo32 = 0;
                #pragma unroll
                for (int e = 0; e < 2; ++e) {
                    int j = 2 * qn + e;
                    float gi = cred[(j*4+0)*33+bbn] + cred[1056+(j*4+0)*33+bbn] + cred[2112+(j*4+0)*33+bbn] + biasA[e][0];
                    float gf = cred[(j*4+1)*33+bbn] + cred[1056+(j*4+1)*33+bbn] + cred[2112+(j*4+1)*33+bbn] + biasA[e][1];
                    float gg = cred[(j*4+2)*33+bbn] + cred[1056+(j*4+2)*33+bbn] + cred[2112+(j*4+2)*33+bbn] + biasA[e][2];
                    float go = cred[(j*4+3)*33+bbn] + cred[1056+(j*4+3)*33+bbn] + cred[2112+(j*4+3)*33+bbn] + biasA[e][3];
                    float ig = sigmoidf_(gi), fg = sigmoidf_(gf);
                    float cg = tanhf_fast(gg), og = sigmoidf_(go);
                    st[e] = st[e] * fg + ig * cg;
                    float h1v = og * tanhf_fast(st[e]);
                    unsigned short h, l;
                    split2(h1v, h, l);
                    hi32 |= ((unsigned)h) << (16 * e);
                    lo32 |= ((unsigned)l) << (16 * e);
                }
                int off = (cu >> 1) * 1024 + (cu & 1) * 512 + bbn * 16 + qn * 4;
                __hip_atomic_store((unsigned*)(exW + off), hi32,
                                   __ATOMIC_RELAXED, __HIP_MEMORY_SCOPE_AGENT);
                __hip_atomic_store((unsigned*)(exW + 32768 + off), lo32,
                                   __ATOMIC_RELAXED, __HIP_MEMORY_SCOPE_AGENT);
            }
        } else {
            if (s >= 1) {      // GRU(s-1): gates from c3+c4 (x-side) and c5 (h-side)
                #pragma unroll
                for (int e = 0; e < 2; ++e) {
                    int j = 2 * qn + e;
                    float rc = cred[3*1056+(j*4+0)*33+bbn] + cred[4*1056+(j*4+0)*33+bbn]
                             + cred[5*1056+(j*4+0)*33+bbn] + biasA[e][0];
                    float zc = cred[3*1056+(j*4+1)*33+bbn] + cred[4*1056+(j*4+1)*33+bbn]
                             + cred[5*1056+(j*4+1)*33+bbn] + biasA[e][1];
                    float xn = cred[3*1056+(j*4+2)*33+bbn] + cred[4*1056+(j*4+2)*33+bbn] + biasA[e][2];
                    float hn = cred[5*1056+(j*4+3)*33+bbn] + biasA[e][3];
                    float rg = sigmoidf_(rc), zg = sigmoidf_(zc);
                    float ng = tanhf_fast(xn + rg * hn);
                    st[e] = zg * st[e] + (1.f - zg) * ng;
                }
            }
            if (s == T_LEN) {
                #pragma unroll
                for (int e = 0; e < 2; ++e)
                    h2out[(size_t)(grp * 32 + bbn) * H_DIM + cu * 8 + 2 * qn + e] = st[e];
            } else {           // publish h2(s-1) (zeros at s==0) as u32 pairs
                unsigned hi32 = 0, lo32 = 0;
                #pragma unroll
                for (int e = 0; e < 2; ++e) {
                    unsigned short h, l;
                    split2(st[e], h, l);
                    hi32 |= ((unsigned)h) << (16 * e);
                    lo32 |= ((unsigned)l) << (16 * e);
                }
                int off = 16384 + (cu >> 1) * 1024 + (cu & 1) * 512 + bbn * 16 + qn * 4;
                __hip_atomic_store((unsigned*)(exW + off), hi32,
                                   __ATOMIC_RELAXED, __HIP_MEMORY_SCOPE_AGENT);
                __hip_atomic_store((unsigned*)(exW + 32768 + off), lo32,
                                   __ATOMIC_RELAXED, __HIP_MEMORY_SCOPE_AGENT);
            }
        }

        if (s == T_LEN) break;

        // ---------------- per-wave drain + arrival ----------------------------
        asm volatile("s_waitcnt vmcnt(0)" ::: "memory");
        if (lane == 0)
            __hip_atomic_fetch_add(&flg[cu], 1, __ATOMIC_RELAXED, __HIP_MEMORY_SCOPE_AGENT);
        // w0: stage x(s+1) (own consumer; off the inter-CU critical path)
        if (wid == 0 && s + 1 < T_LEN) {
            int teff = dir ? (T_LEN - 2 - s) : (s + 1);
            #pragma unroll
            for (int i = 0; i < 4; ++i) {
                int u = i * 64 + lane;
                stage_unit(x, smem_b, b0, teff, u >> 3, u & 7);
            }
        }
    }
}

// out[b][o] = concat(h_fwd[b], h_bwd[b]) . wo[o] + bo[o]
__global__ __launch_bounds__(128)
void brnn_out(const float* __restrict__ h2out, const float* __restrict__ wo,
              const float* __restrict__ bo, float* __restrict__ out)
{
    __shared__ float hc[512];
    int b = blockIdx.x;
    int o = threadIdx.x;
    int btile = b >> 5, bi = b & 31;
    for (int k = threadIdx.x; k < 256; k += 128) {
        hc[k]       = h2out[((size_t)(btile)     * 32 + bi) * H_DIM + k];
        hc[256 + k] = h2out[((size_t)(4 + btile) * 32 + bi) * H_DIM + k];
    }
    __syncthreads();
    float acc = bo[o];
    const float4* w4 = (const float4*)&wo[(size_t)o * 512];
    #pragma unroll 8
    for (int k = 0; k < 128; ++k) {
        float4 w = w4[k];
        acc += w.x * hc[k * 4] + w.y * hc[k * 4 + 1] + w.z * hc[k * 4 + 2] + w.w * hc[k * 4 + 3];
    }
    out[b * 128 + o] = acc;
}

extern "C" void kernel_launch(void* const* d_in, const int* in_sizes, int n_in,
                              void* d_out, int out_size, void* d_ws, size_t ws_size,
                              hipStream_t stream) {
    const float* x   = (const float*)d_in[0];
    const float* w1x = (const float*)d_in[1];
    const float* b1x = (const float*)d_in[2];
    const float* w1h = (const float*)d_in[3];
    const float* b1h = (const float*)d_in[4];
    const float* w2x = (const float*)d_in[5];
    const float* b2x = (const float*)d_in[6];
    const float* w2h = (const float*)d_in[7];
    const float* b2h = (const float*)d_in[8];
    const float* wo  = (const float*)d_in[9];
    const float* bo  = (const float*)d_in[10];
    float* out = (float*)d_out;

    char* ws = (char*)d_ws;
    int* flags = (int*)ws;                          // 8 grp x 64 ints (32 used, packed)
    char* exgb = ws + 4096;                         // 2 par x 8 grp x 64KB = 1MB
    float* h2out = (float*)(ws + 4096 + 1048576);   // 256 x 256 f32 = 256KB

    hipMemsetAsync(flags, 0, 8 * 64 * sizeof(int), stream);

    size_t shmem = LDS_BYTES;
    hipFuncSetAttribute((const void*)brnn_persistent,
                        hipFuncAttributeMaxDynamicSharedMemorySize, (int)shmem);

    void* args[] = { (void*)&x, (void*)&w1x, (void*)&b1x, (void*)&w1h, (void*)&b1h,
                     (void*)&w2x, (void*)&b2x, (void*)&w2h, (void*)&b2h,
                     (void*)&flags, (void*)&exgb, (void*)&h2out };
    hipError_t err = hipLaunchCooperativeKernel((void*)brnn_persistent,
                                                dim3(256), dim3(256), args,
                                                (unsigned int)shmem, stream);
    if (err != hipSuccess) {
        brnn_persistent<<<dim3(256), dim3(256), shmem, stream>>>(
            x, w1x, b1x, w1h, b1h, w2x, b2x, w2h, b2h, flags, exgb, h2out);
    }

    brnn_out<<<dim3(128), dim3(128), 0, stream>>>(h2out, wo, bo, out);
}